// Round 17
// baseline (231.671 us; speedup 1.0000x reference)
//
#include <hip/hip_runtime.h>
#include <hip/hip_bf16.h>

#define Bn 2
#define Tn 2048
#define Cn 1024
#define Hn 16
#define Dn 64
#define Mrows (Bn * Tn)   // 4096

typedef __attribute__((ext_vector_type(8))) short short8;
typedef __attribute__((ext_vector_type(4))) float f32x4;

typedef const __attribute__((address_space(1))) unsigned int* gas_ptr;
typedef __attribute__((address_space(3))) unsigned int* las_ptr;

__device__ __forceinline__ unsigned short f2b(float f) {
  unsigned int u = __builtin_bit_cast(unsigned int, f);
  return (unsigned short)((u + 0x7fffu + ((u >> 16) & 1u)) >> 16);
}

__device__ __forceinline__ float gelu_f(float v) {
  float u2 = v + 0.044715f * v * v * v;
  float e = __expf(1.5957691216f * u2);
  float th = 1.0f - 2.0f / (e + 1.0f);
  return 0.5f * v * (1.0f + th);
}

// ---------------- LayerNorm row body ----------------
__device__ __forceinline__ void ln_row(const float* __restrict__ x, const float* __restrict__ w,
                                       const float* __restrict__ b, unsigned short* __restrict__ out,
                                       int row, float* ls, float* ls2) {
  const int t = threadIdx.x;
  const float4 v = *reinterpret_cast<const float4*>(x + (size_t)row * Cn + t * 4);
  float s = v.x + v.y + v.z + v.w;
  float s2 = v.x * v.x + v.y * v.y + v.z * v.z + v.w * v.w;
#pragma unroll
  for (int m = 1; m < 64; m <<= 1) { s += __shfl_xor(s, m); s2 += __shfl_xor(s2, m); }
  if ((t & 63) == 0) { ls[t >> 6] = s; ls2[t >> 6] = s2; }
  __syncthreads();
  s  = ls[0] + ls[1] + ls[2] + ls[3];
  s2 = ls2[0] + ls2[1] + ls2[2] + ls2[3];
  const float mu = s * (1.0f / Cn);
  const float rstd = rsqrtf(s2 * (1.0f / Cn) - mu * mu + 1e-5f);
  const float4 wv = *reinterpret_cast<const float4*>(w + t * 4);
  const float4 bv = *reinterpret_cast<const float4*>(b + t * 4);
  unsigned short o[4];
  o[0] = f2b((v.x - mu) * rstd * wv.x + bv.x);
  o[1] = f2b((v.y - mu) * rstd * wv.y + bv.y);
  o[2] = f2b((v.z - mu) * rstd * wv.z + bv.z);
  o[3] = f2b((v.w - mu) * rstd * wv.w + bv.w);
  *reinterpret_cast<uint2*>(out + (size_t)row * Cn + t * 4) = *reinterpret_cast<uint2*>(o);
}

__global__ __launch_bounds__(256) void ln_kernel(const float* __restrict__ x,
                                                 const float* __restrict__ w,
                                                 const float* __restrict__ b,
                                                 unsigned short* __restrict__ out) {
  __shared__ float ls[4], ls2[4];
  ln_row(x, w, b, out, blockIdx.x, ls, ls2);
}

// ---------------- prep: 4 weight transposes + LN1 fused ----------------
__global__ __launch_bounds__(256) void prep_kernel(
    const float* __restrict__ W0, unsigned short* __restrict__ T0,
    const float* __restrict__ W1, unsigned short* __restrict__ T1,
    const float* __restrict__ W2, unsigned short* __restrict__ T2,
    const float* __restrict__ W3, unsigned short* __restrict__ T3,
    const float* __restrict__ x, const float* __restrict__ ln1w,
    const float* __restrict__ ln1b, unsigned short* __restrict__ h) {
  __shared__ float tile[32][33];
  __shared__ float ls[4], ls2[4];
  int b = blockIdx.x;
  if (b >= 12288) {
    ln_row(x, ln1w, ln1b, h, b - 12288, ls, ls2);
    return;
  }
  const float* W; unsigned short* T; int K, N;
  if (b < 3072)      { W = W0; T = T0; K = 1024; N = 3072; }
  else if (b < 4096) { W = W1; T = T1; K = 1024; N = 1024; b -= 3072; }
  else if (b < 8192) { W = W2; T = T2; K = 1024; N = 4096; b -= 4096; }
  else               { W = W3; T = T3; K = 4096; N = 1024; b -= 8192; }
  const int nx = N >> 5;
  const int n0 = (b % nx) * 32, k0 = (b / nx) * 32;
  const int tx = threadIdx.x & 31, ty = threadIdx.x >> 5;
#pragma unroll
  for (int r = 0; r < 4; r++)
    tile[ty + r * 8][tx] = W[(size_t)(k0 + ty + r * 8) * N + n0 + tx];
  __syncthreads();
#pragma unroll
  for (int r = 0; r < 4; r++)
    T[(size_t)(n0 + ty + r * 8) * K + k0 + tx] = f2b(tile[tx][ty + r * 8]);
}

// ---------------- 256x192 8-wave slim-sync GEMM (qkv) — R17: exact per-wave waits ----------
template <int EP>
__global__ __launch_bounds__(512, 1) void gemm192_kernel(
    const unsigned short* __restrict__ A, const unsigned short* __restrict__ Bt,
    const float* __restrict__ bias, void* out, int M, int N, int K, int nx) {
  extern __shared__ unsigned short lds[];
  const int tid = threadIdx.x;
  const int lane = tid & 63, w = tid >> 6;
  const int wm = w >> 2, wn = w & 3;
  const int l15 = lane & 15, l4 = lane >> 4;

  const int nwg = gridDim.x;
  int wg = blockIdx.x;
  wg = (wg & 7) * (nwg >> 3) + (wg >> 3);
  const int tile_m = (wg / nx) * 256;
  const int tile_n = (wg % nx) * 192;

  f32x4 acc[8][3] = {};

  const bool isA = (w < 4);
  const int wl = w & 3;
  const int ch0 = wl * 64 + lane;
  const int r0 = ch0 >> 2;
  const int c0 = (((ch0 & 3) ^ ((r0 >> 1) & 3))) * 8;
  const unsigned short* G = isA ? A : Bt;
  const int tb0 = isA ? tile_m : tile_n;
  const unsigned short* g0 = G + (size_t)(tb0 + r0) * K + c0;
  const int lb = wl * 512;

  auto stage = [&](int slot, int t) {
    unsigned short* L = lds + slot * 14336 + (isA ? 0 : 8192);
    const size_t ko = (size_t)t * 32;
#pragma unroll
    for (int j = 0; j < 4; j++) {
      if (isA || j < 3)
        __builtin_amdgcn_global_load_lds((gas_ptr)(g0 + (size_t)64 * K * j + ko),
                                         (las_ptr)&L[lb + j * 2048], 16, 0, 0);
    }
  };

  stage(0, 0);
  stage(1, 1);
  stage(2, 2);
  if (isA) asm volatile("s_waitcnt vmcnt(8)" ::: "memory");
  else     asm volatile("s_waitcnt vmcnt(6)" ::: "memory");
  __builtin_amdgcn_s_barrier();
  __builtin_amdgcn_sched_barrier(0);

  const int ca = (l4 ^ ((l15 >> 1) & 3)) * 8;

  const int nt = K >> 5;
  for (int tb = 0; tb < nt; tb += 4) {
#pragma unroll
    for (int u = 0; u < 4; u++) {
      const int t = tb + u;
      if (t + 3 < nt) stage((u + 3) & 3, t + 3);

      const unsigned short* Ab = lds + u * 14336;
      const unsigned short* Bb = Ab + 8192;
      short8 a[4], b[3], a2[4];
#pragma unroll
      for (int i = 0; i < 4; i++)
        a[i] = *reinterpret_cast<const short8*>(&Ab[(wm * 128 + i * 16 + l15) * 32 + ca]);
#pragma unroll
      for (int i = 0; i < 3; i++)
        b[i] = *reinterpret_cast<const short8*>(&Bb[(wn * 48 + i * 16 + l15) * 32 + ca]);
      __builtin_amdgcn_sched_barrier(0);
#pragma unroll
      for (int i = 0; i < 4; i++)
        a2[i] = *reinterpret_cast<const short8*>(&Ab[(wm * 128 + 64 + i * 16 + l15) * 32 + ca]);

      asm volatile("s_waitcnt lgkmcnt(4)" ::: "memory");
      __builtin_amdgcn_sched_barrier(0);
      __builtin_amdgcn_s_setprio(1);
#pragma unroll
      for (int mi = 0; mi < 4; mi++)
#pragma unroll
        for (int ni = 0; ni < 3; ni++)
          acc[mi][ni] = __builtin_amdgcn_mfma_f32_16x16x32_bf16(a[mi], b[ni], acc[mi][ni], 0, 0, 0);
      __builtin_amdgcn_s_setprio(0);
      __builtin_amdgcn_sched_barrier(0);

      asm volatile("s_waitcnt lgkmcnt(0)" ::: "memory");
      __builtin_amdgcn_sched_barrier(0);
      __builtin_amdgcn_s_setprio(1);
#pragma unroll
      for (int mi = 0; mi < 4; mi++)
#pragma unroll
        for (int ni = 0; ni < 3; ni++)
          acc[mi + 4][ni] = __builtin_amdgcn_mfma_f32_16x16x32_bf16(a2[mi], b[ni], acc[mi + 4][ni], 0, 0, 0);
      __builtin_amdgcn_s_setprio(0);
      __builtin_amdgcn_sched_barrier(0);

      if (t + 3 < nt) {
        if (isA) asm volatile("s_waitcnt vmcnt(8)" ::: "memory");
        else     asm volatile("s_waitcnt vmcnt(6)" ::: "memory");
      } else if (t + 2 < nt) {
        if (isA) asm volatile("s_waitcnt vmcnt(4)" ::: "memory");
        else     asm volatile("s_waitcnt vmcnt(3)" ::: "memory");
      } else if (t + 1 < nt) {
        asm volatile("s_waitcnt vmcnt(0)" ::: "memory");
      }
      __builtin_amdgcn_s_barrier();
      __builtin_amdgcn_sched_barrier(0);
    }
  }

#pragma unroll
  for (int ni = 0; ni < 3; ni++) {
    const int col = tile_n + wn * 48 + ni * 16 + l15;
    const float bv = bias[col];
#pragma unroll
    for (int mi = 0; mi < 8; mi++) {
#pragma unroll
      for (int r = 0; r < 4; r++) {
        const int row = tile_m + wm * 128 + mi * 16 + l4 * 4 + r;
        const size_t idx = (size_t)row * N + col;
        float v = acc[mi][ni][r] + bv;
        if (EP == 0) {
          ((unsigned short*)out)[idx] = f2b(v);
        } else {
          ((unsigned short*)out)[idx] = f2b(gelu_f(v));
        }
      }
    }
  }
}

// ---------------- 128^2 GEMM — R13 pair-processing, templated epilogue ----------------
// EP=1: f32 out = v + bias + res (res may alias out; read-once-write-once per idx).
// EP=2: bf16 out = gelu(v + bias)  (fc: grid 32x32 = 1024 blocks).
template <int EP>
__global__ __launch_bounds__(512, 1) void gemm128_kernel(
    const unsigned short* __restrict__ A, const unsigned short* __restrict__ Bt,
    const float* __restrict__ bias, const float* __restrict__ res, void* __restrict__ outv,
    int M, int N, int K, int nx) {
  extern __shared__ unsigned short lds[];
  const int tid = threadIdx.x;
  const int lane = tid & 63, w = tid >> 6;
  const int wm = w >> 2, wn = w & 3;
  const int l15 = lane & 15, l4 = lane >> 4;

  const int nwg = gridDim.x;
  int wg = blockIdx.x;
  wg = (wg & 7) * (nwg >> 3) + (wg >> 3);
  const int tile_m = (wg / nx) * 128;
  const int tile_n = (wg % nx) * 128;

  f32x4 acc[4][2] = {};

  const unsigned short* Gs = (w < 4) ? A : Bt;
  const int tb0 = (w < 4) ? tile_m : tile_n;
  const int ch0 = (w & 3) * 128 + lane;
  const int r0c = ch0 >> 2;
  const int c0s = (((ch0 & 3) ^ ((r0c >> 1) & 3))) * 8;
  const unsigned short* g0 = Gs + (size_t)(tb0 + r0c) * K + c0s;
  const unsigned short* g1 = g0 + (size_t)16 * K;
  const int lds0 = ((w & 3) * 128) * 8, lds1 = ((w & 3) * 128 + 64) * 8;
  const int half = (w < 4) ? 0 : 4096;

  auto stage = [&](int slot, int t) {
    unsigned short* Lb = lds + slot * 8192 + half;
    const size_t ko = (size_t)t * 32;
    __builtin_amdgcn_global_load_lds((gas_ptr)(g0 + ko), (las_ptr)&Lb[lds0], 16, 0, 0);
    __builtin_amdgcn_global_load_lds((gas_ptr)(g1 + ko), (las_ptr)&Lb[lds1], 16, 0, 0);
  };

  stage(0, 0);
  stage(1, 1);
  stage(2, 2);
  stage(3, 3);
  asm volatile("s_waitcnt vmcnt(4)" ::: "memory");
  __builtin_amdgcn_s_barrier();
  __builtin_amdgcn_sched_barrier(0);

  const int ca = (l4 ^ ((l15 >> 1) & 3)) * 8;

  const int nt = K >> 5;
  const int np = nt >> 1;
  for (int p = 0; p < np; ++p) {
    const int t0 = 2 * p;
    if (t0 + 4 < nt) stage((t0 + 4) % 6, t0 + 4);
    if (t0 + 5 < nt) stage((t0 + 5) % 6, t0 + 5);

    const unsigned short* A0 = lds + (t0 % 6) * 8192;
    const unsigned short* B0 = A0 + 4096;
    const unsigned short* A1 = lds + ((t0 + 1) % 6) * 8192;
    const unsigned short* B1 = A1 + 4096;
    short8 a[2], b[2], a2[2], c[2], d[2], c2[2];
#pragma unroll
    for (int i = 0; i < 2; i++) {
      a[i] = *reinterpret_cast<const short8*>(&A0[(wm * 64 + i * 16 + l15) * 32 + ca]);
      b[i] = *reinterpret_cast<const short8*>(&B0[(wn * 32 + i * 16 + l15) * 32 + ca]);
    }
    __builtin_amdgcn_sched_barrier(0);
#pragma unroll
    for (int i = 0; i < 2; i++)
      a2[i] = *reinterpret_cast<const short8*>(&A0[(wm * 64 + 32 + i * 16 + l15) * 32 + ca]);
    __builtin_amdgcn_sched_barrier(0);
#pragma unroll
    for (int i = 0; i < 2; i++) {
      c[i] = *reinterpret_cast<const short8*>(&A1[(wm * 64 + i * 16 + l15) * 32 + ca]);
      d[i] = *reinterpret_cast<const short8*>(&B1[(wn * 32 + i * 16 + l15) * 32 + ca]);
    }
    __builtin_amdgcn_sched_barrier(0);
#pragma unroll
    for (int i = 0; i < 2; i++)
      c2[i] = *reinterpret_cast<const short8*>(&A1[(wm * 64 + 32 + i * 16 + l15) * 32 + ca]);

    asm volatile("s_waitcnt lgkmcnt(8)" ::: "memory");
    __builtin_amdgcn_sched_barrier(0);
    __builtin_amdgcn_s_setprio(1);
#pragma unroll
    for (int mi = 0; mi < 2; mi++)
#pragma unroll
      for (int ni = 0; ni < 2; ni++)
        acc[mi][ni] = __builtin_amdgcn_mfma_f32_16x16x32_bf16(a[mi], b[ni], acc[mi][ni], 0, 0, 0);
    __builtin_amdgcn_s_setprio(0);
    __builtin_amdgcn_sched_barrier(0);

    asm volatile("s_waitcnt lgkmcnt(6)" ::: "memory");
    __builtin_amdgcn_sched_barrier(0);
    __builtin_amdgcn_s_setprio(1);
#pragma unroll
    for (int mi = 0; mi < 2; mi++)
#pragma unroll
      for (int ni = 0; ni < 2; ni++)
        acc[mi + 2][ni] = __builtin_amdgcn_mfma_f32_16x16x32_bf16(a2[mi], b[ni], acc[mi + 2][ni], 0, 0, 0);
    __builtin_amdgcn_s_setprio(0);
    __builtin_amdgcn_sched_barrier(0);

    asm volatile("s_waitcnt lgkmcnt(2)" ::: "memory");
    __builtin_amdgcn_sched_barrier(0);
    __builtin_amdgcn_s_setprio(1);
#pragma unroll
    for (int mi = 0; mi < 2; mi++)
#pragma unroll
      for (int ni = 0; ni < 2; ni++)
        acc[mi][ni] = __builtin_amdgcn_mfma_f32_16x16x32_bf16(c[mi], d[ni], acc[mi][ni], 0, 0, 0);
    __builtin_amdgcn_s_setprio(0);
    __builtin_amdgcn_sched_barrier(0);

    asm volatile("s_waitcnt lgkmcnt(0)" ::: "memory");
    __builtin_amdgcn_sched_barrier(0);
    __builtin_amdgcn_s_setprio(1);
#pragma unroll
    for (int mi = 0; mi < 2; mi++)
#pragma unroll
      for (int ni = 0; ni < 2; ni++)
        acc[mi + 2][ni] = __builtin_amdgcn_mfma_f32_16x16x32_bf16(c2[mi], d[ni], acc[mi + 2][ni], 0, 0, 0);
    __builtin_amdgcn_s_setprio(0);
    __builtin_amdgcn_sched_barrier(0);

    if (t0 + 4 < nt) {
      asm volatile("s_waitcnt vmcnt(4)" ::: "memory");
    } else if (t0 + 2 < nt) {
      asm volatile("s_waitcnt vmcnt(0)" ::: "memory");
    }
    __builtin_amdgcn_s_barrier();
    __builtin_amdgcn_sched_barrier(0);
  }

#pragma unroll
  for (int ni = 0; ni < 2; ni++) {
    const int col = tile_n + wn * 32 + ni * 16 + l15;
    const float bv = bias[col];
#pragma unroll
    for (int mi = 0; mi < 4; mi++) {
#pragma unroll
      for (int r = 0; r < 4; r++) {
        const int row = tile_m + wm * 64 + mi * 16 + l4 * 4 + r;
        const size_t idx = (size_t)row * N + col;
        float v = acc[mi][ni][r] + bv;
        if (EP == 1) {
          ((float*)outv)[idx] = v + res[idx];
        } else {
          ((unsigned short*)outv)[idx] = f2b(gelu_f(v));
        }
      }
    }
  }
}

// ---------------- Strided-sparse flash attention v3 + T13 — R17 counted barriers ----------
// Loop barriers use counted vmcnt (telescoping): mid = vmcnt(4) [K(t) landed — issued a
// full iteration earlier; leave fetchV(t+1)+stageK(t+1)=4 in flight]; end = vmcnt(2)
// [drain fetchV(t+1) -> vr valid for next V-write; leave stageK(t+1)=2 flying into next
// mid]. WAR edges unchanged (lgkm(0)+barrier before every LDS overwrite).
__global__ __launch_bounds__(256, 4) void attn_kernel(const unsigned short* __restrict__ qkv,
                                                      unsigned short* __restrict__ y) {
  __shared__ unsigned short SH[17408];
  const int tid = threadIdx.x;
  const int lane = tid & 63, w = tid >> 6;
  const int l15 = lane & 15, l4 = lane >> 4;

  const int bi = blockIdx.x;
  const int quarter = bi >> 8, rest = bi & 255;
  const int bh = rest >> 3, sub = rest & 7;
  int qt;
  if (quarter == 0) qt = sub;
  else if (quarter == 1) qt = 15 - sub;
  else if (quarter == 2) qt = 16 + sub;
  else qt = 31 - sub;
  const int bb = bh >> 4, hh = bh & 15;
  const int q0 = qt * 64;
  const size_t base = (size_t)bb * Tn * (3 * Cn) + hh * 64;

  const int nfar = qt >> 1;
  const int ntiles = nfar + (q0 ? 2 : 1);

  unsigned short* Vt = SH + 8192;
  unsigned short* Ps = SH + 12800 + w * 1152;

  auto keyof = [&](int t, int row) -> int {
    if (t < nfar) return t * 128 + 2 * row;
    return q0 - 64 * (ntiles - 1 - t) + row;
  };
  auto stageK = [&](int t) {
    unsigned short* kb = SH + ((t & 1) << 12);
#pragma unroll
    for (int u = 0; u < 2; u++) {
      const int chunk = u * 256 + tid;
      const int row = chunk >> 3, cc = chunk & 7;
      const int csrc = cc ^ (row & 7);
      const int key = keyof(t, row);
      __builtin_amdgcn_global_load_lds(
          (gas_ptr)&qkv[base + Cn + (size_t)key * (3 * Cn) + csrc * 8],
          (las_ptr)&kb[(u * 256 + (w << 6)) * 8], 16, 0, 0);
    }
  };
  uint4 vr[2];
  auto fetchV = [&](int t) {
#pragma unroll
    for (int u = 0; u < 2; u++) {
      const int chunk = u * 256 + tid;
      const int row = chunk >> 3, cc = chunk & 7;
      const int key = keyof(t, row);
      vr[u] = *reinterpret_cast<const uint4*>(&qkv[base + 2 * Cn + (size_t)key * (3 * Cn) + cc * 8]);
    }
  };

#pragma unroll
  for (int u = 0; u < 2; u++) {
    const int chunk = u * 256 + tid;
    const int row = chunk >> 3, cc = chunk & 7;
    const int csrc = cc ^ (row & 7);
    __builtin_amdgcn_global_load_lds(
        (gas_ptr)&qkv[base + (size_t)(q0 + row) * (3 * Cn) + csrc * 8],
        (las_ptr)&SH[(u * 256 + (w << 6)) * 8], 16, 0, 0);
  }
  __syncthreads();
  short8 qf[2];
#pragma unroll
  for (int ks = 0; ks < 2; ks++) {
    const int r = (w << 4) + l15;
    qf[ks] = *reinterpret_cast<const short8*>(&SH[r * 64 + (((ks * 4 + l4) ^ (l15 & 7)) * 8)]);
  }
  asm volatile("s_waitcnt lgkmcnt(0)" ::: "memory");
  __builtin_amdgcn_s_barrier();
  __builtin_amdgcn_sched_barrier(0);
  stageK(0);
  fetchV(0);
  __syncthreads();   // prologue drain: K(0) + vr(0) landed

  f32x4 acc_o[4] = {};
  float mrow[4], lrow[4];
#pragma unroll
  for (int r = 0; r < 4; r++) { mrow[r] = -1e30f; lrow[r] = 0.0f; }

  for (int t = 0; t < ntiles; ++t) {
    // 1. write V(t) from vr (swizzled transpose)
#pragma unroll
    for (int u = 0; u < 2; u++) {
      const int chunk = u * 256 + tid;
      const int row = chunk >> 3, cc = chunk & 7;
      unsigned short tmp[8];
      *reinterpret_cast<uint4*>(tmp) = vr[u];
      const int xr = row ^ (cc << 3);
#pragma unroll
      for (int j = 0; j < 8; j++) Vt[(cc * 8 + j) * 72 + xr] = tmp[j];
    }
    // 2./3. prefetch t+1 (fetchV FIRST so end-of-iter vmcnt(2) drains it)
    if (t + 1 < ntiles) { fetchV(t + 1); stageK(t + 1); }
    __builtin_amdgcn_sched_barrier(0);
    // 4. mid barrier: V(t) visible + K(t) published; prefetch stays in flight
    if (t + 1 < ntiles) {
      asm volatile("s_waitcnt vmcnt(4) lgkmcnt(0)" ::: "memory");
    } else {
      asm volatile("s_waitcnt vmcnt(0) lgkmcnt(0)" ::: "memory");
    }
    __builtin_amdgcn_s_barrier();
    __builtin_amdgcn_sched_barrier(0);

    const unsigned short* Kb = SH + ((t & 1) << 12);
    f32x4 s[4] = {};
#pragma unroll
    for (int ni = 0; ni < 4; ni++) {
#pragma unroll
      for (int ks = 0; ks < 2; ks++) {
        const int r = ni * 16 + l15;
        short8 kf = *reinterpret_cast<const short8*>(&Kb[r * 64 + (((ks * 4 + l4) ^ (l15 & 7)) * 8)]);
        s[ni] = __builtin_amdgcn_mfma_f32_16x16x32_bf16(qf[ks], kf, s[ni], 0, 0, 0);
      }
    }

    const bool far = (t < nfar);
    const int kb0 = far ? t * 128 : q0 - 64 * (ntiles - 1 - t);
#pragma unroll
    for (int ni = 0; ni < 4; ni++) {
      const int pos = ni * 16 + l15;
      const int j = far ? kb0 + 2 * pos : kb0 + pos;
#pragma unroll
      for (int r = 0; r < 4; r++) {
        float v = s[ni][r] * 0.125f;
        if (far) {
          v = (j < q0 - 64) ? v : -1e30f;
        } else {
          const int iq = q0 + (w << 4) + l4 * 4 + r;
          const bool ok = (j <= iq) && ((j >= iq - 4) || ((j & 1) == 0));
          v = ok ? v : -1e30f;
        }
        s[ni][r] = v;
      }
    }

    float tmx[4];
    bool need = false;
#pragma unroll
    for (int r = 0; r < 4; r++) {
      float tm = fmaxf(fmaxf(s[0][r], s[1][r]), fmaxf(s[2][r], s[3][r]));
      tm = fmaxf(tm, __shfl_xor(tm, 1));
      tm = fmaxf(tm, __shfl_xor(tm, 2));
      tm = fmaxf(tm, __shfl_xor(tm, 4));
      tm = fmaxf(tm, __shfl_xor(tm, 8));
      tmx[r] = tm;
      need = need || (tm > mrow[r] + 8.0f);
    }
    if (__any(need)) {
#pragma unroll
      for (int r = 0; r < 4; r++) {
        const float mnew = fmaxf(mrow[r], tmx[r]);
        const float alpha = __expf(mrow[r] - mnew);
        mrow[r] = mnew;
        lrow[r] *= alpha;
#pragma unroll
        for (int nd = 0; nd < 4; nd++) acc_o[nd][r] *= alpha;
      }
    }
#pragma unroll
    for (int r = 0; r < 4; r++) {
      float rs = 0.0f;
#pragma unroll
      for (int ni = 0; ni < 4; ni++) {
        const float pv = __expf(s[ni][r] - mrow[r]);
        s[ni][r] = pv;
        rs += pv;
      }
      rs += __shfl_xor(rs, 1); rs += __shfl_xor(rs, 2);
      rs += __shfl_xor(rs, 4); rs += __shfl_xor(rs, 8);
      lrow[r] += rs;
    }

#pragma unroll
    for (int ni = 0; ni < 4; ni++)
#pragma unroll
      for (int r = 0; r < 4; r++)
        Ps[(l4 * 4 + r) * 72 + ni * 16 + l15] = f2b(s[ni][r]);

#pragma unroll
    for (int kss = 0; kss < 2; kss++) {
      short8 pf = *reinterpret_cast<const short8*>(&Ps[l15 * 72 + kss * 32 + l4 * 8]);
#pragma unroll
      for (int nd = 0; nd < 4; nd++) {
        const int d = nd * 16 + l15;
        const int kcol = (kss * 32 + l4 * 8) ^ ((d >> 3) << 3);
        short8 vf = *reinterpret_cast<const short8*>(&Vt[d * 72 + kcol]);
        acc_o[nd] = __builtin_amdgcn_mfma_f32_16x16x32_bf16(pf, vf, acc_o[nd], 0, 0, 0);
      }
    }

    // 7. end barrier: vr(t+1) landed (vmcnt(2) drains fetchV), DS reads done;
    //    stageK(t+1) stays in flight, published at next mid barrier.
    if (t + 1 < ntiles) {
      asm volatile("s_waitcnt vmcnt(2) lgkmcnt(0)" ::: "memory");
    } else {
      asm volatile("s_waitcnt lgkmcnt(0)" ::: "memory");
    }
    __builtin_amdgcn_s_barrier();
    __builtin_amdgcn_sched_barrier(0);
  }

#pragma unroll
  for (int r = 0; r < 4; r++) {
    const float inv = 1.0f / lrow[r];
    const int row = q0 + (w << 4) + l4 * 4 + r;
#pragma unroll
    for (int nd = 0; nd < 4; nd++) {
      const int col = nd * 16 + l15;
      y[((size_t)bb * Tn + row) * Cn + hh * 64 + col] = f2b(acc_o[nd][r] * inv);
    }
  }
}

// ---------------- launch ----------------
extern "C" void kernel_launch(void* const* d_in, const int* in_sizes, int n_in,
                              void* d_out, int out_size, void* d_ws, size_t ws_size,
                              hipStream_t stream) {
  const float* x           = (const float*)d_in[0];
  const float* ln1_w       = (const float*)d_in[1];
  const float* ln1_b       = (const float*)d_in[2];
  const float* c_attn_w    = (const float*)d_in[3];
  const float* c_attn_b    = (const float*)d_in[4];
  const float* attn_proj_w = (const float*)d_in[5];
  const float* attn_proj_b = (const float*)d_in[6];
  const float* ln2_w       = (const float*)d_in[7];
  const float* ln2_b       = (const float*)d_in[8];
  const float* fc_w        = (const float*)d_in[9];
  const float* fc_b        = (const float*)d_in[10];
  const float* mlp_proj_w  = (const float*)d_in[11];
  const float* mlp_proj_b  = (const float*)d_in[12];
  float* out = (float*)d_out;

  char* ws = (char*)d_ws;
  unsigned short* wT1 = (unsigned short*)(ws);                     // [3072][1024]
  unsigned short* wT2 = (unsigned short*)(ws + 6291456);           // [1024][1024]
  unsigned short* wT3 = (unsigned short*)(ws + 8388608);           // [4096][1024]
  unsigned short* wT4 = (unsigned short*)(ws + 16777216);          // [1024][4096]
  unsigned short* h   = (unsigned short*)(ws + 25165824);          // [4096][1024]
  unsigned short* qkv = (unsigned short*)(ws + 33554432);          // [4096][3072] / [4096][4096]
  unsigned short* yb  = (unsigned short*)(ws + 67108864);          // [4096][1024]

  hipFuncSetAttribute((const void*)gemm192_kernel<0>, hipFuncAttributeMaxDynamicSharedMemorySize, 114688);
  hipFuncSetAttribute((const void*)gemm128_kernel<1>, hipFuncAttributeMaxDynamicSharedMemorySize, 98304);
  hipFuncSetAttribute((const void*)gemm128_kernel<2>, hipFuncAttributeMaxDynamicSharedMemorySize, 98304);

  prep_kernel<<<16384, 256, 0, stream>>>(c_attn_w, wT1, attn_proj_w, wT2,
                                         fc_w, wT3, mlp_proj_w, wT4,
                                         x, ln1_w, ln1_b, h);
  // qkv = h @ c_attn_w + b   (256x192 tile, grid 256)
  gemm192_kernel<0><<<(Mrows / 256) * (3072 / 192), 512, 114688, stream>>>(
      h, wT1, c_attn_b, qkv, Mrows, 3072, 1024, 3072 / 192);
  attn_kernel<<<1024, 256, 0, stream>>>(qkv, yb);
  // x1 = x + y @ attn_proj_w + b
  gemm128_kernel<1><<<(Mrows / 128) * (1024 / 128), 512, 98304, stream>>>(
      yb, wT2, attn_proj_b, x, out, Mrows, 1024, 1024, 1024 / 128);
  ln_kernel<<<Mrows, 256, 0, stream>>>(out, ln2_w, ln2_b, h);
  // a = gelu(h2 @ fc_w + b)   (now gemm128 pair schedule, grid 32x32 = 1024)
  gemm128_kernel<2><<<(Mrows / 128) * (4096 / 128), 512, 98304, stream>>>(
      h, wT3, fc_b, nullptr, qkv, Mrows, 4096, 1024, 4096 / 128);
  // out = x1 + a @ mlp_proj_w + b
  gemm128_kernel<1><<<(Mrows / 128) * (1024 / 128), 512, 98304, stream>>>(
      qkv, wT4, mlp_proj_b, out, out, Mrows, 1024, 4096, 1024 / 128);
}

// Round 18
// 217.223 us; speedup vs baseline: 1.0665x; 1.0665x over previous
//
#include <hip/hip_runtime.h>
#include <hip/hip_bf16.h>

#define Bn 2
#define Tn 2048
#define Cn 1024
#define Hn 16
#define Dn 64
#define Mrows (Bn * Tn)   // 4096

typedef __attribute__((ext_vector_type(8))) short short8;
typedef __attribute__((ext_vector_type(4))) float f32x4;

typedef const __attribute__((address_space(1))) unsigned int* gas_ptr;
typedef __attribute__((address_space(3))) unsigned int* las_ptr;

__device__ __forceinline__ unsigned short f2b(float f) {
  unsigned int u = __builtin_bit_cast(unsigned int, f);
  return (unsigned short)((u + 0x7fffu + ((u >> 16) & 1u)) >> 16);
}

__device__ __forceinline__ float gelu_f(float v) {
  float u2 = v + 0.044715f * v * v * v;
  float e = __expf(1.5957691216f * u2);
  float th = 1.0f - 2.0f / (e + 1.0f);
  return 0.5f * v * (1.0f + th);
}

// ---------------- LayerNorm row body ----------------
__device__ __forceinline__ void ln_row(const float* __restrict__ x, const float* __restrict__ w,
                                       const float* __restrict__ b, unsigned short* __restrict__ out,
                                       int row, float* ls, float* ls2) {
  const int t = threadIdx.x;
  const float4 v = *reinterpret_cast<const float4*>(x + (size_t)row * Cn + t * 4);
  float s = v.x + v.y + v.z + v.w;
  float s2 = v.x * v.x + v.y * v.y + v.z * v.z + v.w * v.w;
#pragma unroll
  for (int m = 1; m < 64; m <<= 1) { s += __shfl_xor(s, m); s2 += __shfl_xor(s2, m); }
  if ((t & 63) == 0) { ls[t >> 6] = s; ls2[t >> 6] = s2; }
  __syncthreads();
  s  = ls[0] + ls[1] + ls[2] + ls[3];
  s2 = ls2[0] + ls2[1] + ls2[2] + ls2[3];
  const float mu = s * (1.0f / Cn);
  const float rstd = rsqrtf(s2 * (1.0f / Cn) - mu * mu + 1e-5f);
  const float4 wv = *reinterpret_cast<const float4*>(w + t * 4);
  const float4 bv = *reinterpret_cast<const float4*>(b + t * 4);
  unsigned short o[4];
  o[0] = f2b((v.x - mu) * rstd * wv.x + bv.x);
  o[1] = f2b((v.y - mu) * rstd * wv.y + bv.y);
  o[2] = f2b((v.z - mu) * rstd * wv.z + bv.z);
  o[3] = f2b((v.w - mu) * rstd * wv.w + bv.w);
  *reinterpret_cast<uint2*>(out + (size_t)row * Cn + t * 4) = *reinterpret_cast<uint2*>(o);
}

__global__ __launch_bounds__(256) void ln_kernel(const float* __restrict__ x,
                                                 const float* __restrict__ w,
                                                 const float* __restrict__ b,
                                                 unsigned short* __restrict__ out) {
  __shared__ float ls[4], ls2[4];
  ln_row(x, w, b, out, blockIdx.x, ls, ls2);
}

// ---------------- prep: 4 weight transposes + LN1 fused ----------------
__global__ __launch_bounds__(256) void prep_kernel(
    const float* __restrict__ W0, unsigned short* __restrict__ T0,
    const float* __restrict__ W1, unsigned short* __restrict__ T1,
    const float* __restrict__ W2, unsigned short* __restrict__ T2,
    const float* __restrict__ W3, unsigned short* __restrict__ T3,
    const float* __restrict__ x, const float* __restrict__ ln1w,
    const float* __restrict__ ln1b, unsigned short* __restrict__ h) {
  __shared__ float tile[32][33];
  __shared__ float ls[4], ls2[4];
  int b = blockIdx.x;
  if (b >= 12288) {
    ln_row(x, ln1w, ln1b, h, b - 12288, ls, ls2);
    return;
  }
  const float* W; unsigned short* T; int K, N;
  if (b < 3072)      { W = W0; T = T0; K = 1024; N = 3072; }
  else if (b < 4096) { W = W1; T = T1; K = 1024; N = 1024; b -= 3072; }
  else if (b < 8192) { W = W2; T = T2; K = 1024; N = 4096; b -= 4096; }
  else               { W = W3; T = T3; K = 4096; N = 1024; b -= 8192; }
  const int nx = N >> 5;
  const int n0 = (b % nx) * 32, k0 = (b / nx) * 32;
  const int tx = threadIdx.x & 31, ty = threadIdx.x >> 5;
#pragma unroll
  for (int r = 0; r < 4; r++)
    tile[ty + r * 8][tx] = W[(size_t)(k0 + ty + r * 8) * N + n0 + tx];
  __syncthreads();
#pragma unroll
  for (int r = 0; r < 4; r++)
    T[(size_t)(n0 + ty + r * 8) * K + k0 + tx] = f2b(tile[tx][ty + r * 8]);
}

// ---------------- 256^2 8-wave pipelined GEMM — R12/R13 slim-sync (fc) ----------------
#define BUFS 16384
template <int EP>
__global__ __launch_bounds__(512, 2) void gemm256_kernel(
    const unsigned short* __restrict__ A, const unsigned short* __restrict__ Bt,
    const float* __restrict__ bias, void* out, int M, int N, int K, int nx) {
  extern __shared__ unsigned short lds[];
  const int tid = threadIdx.x;
  const int lane = tid & 63, w = tid >> 6;
  const int wm = w >> 2, wn = w & 3;
  const int l15 = lane & 15, l4 = lane >> 4;

  const int nwg = gridDim.x;
  int wg = blockIdx.x;
  wg = (wg & 7) * (nwg >> 3) + (wg >> 3);
  const int tile_m = (wg / nx) * 256;
  const int tile_n = (wg % nx) * 256;

  f32x4 acc[8][4] = {};

  const int ch0 = w * 64 + lane;
  const int r0 = ch0 >> 2;
  const int c0 = (((ch0 & 3) ^ ((r0 >> 1) & 3))) * 8;
  const unsigned short* gA0 = A + (size_t)(tile_m + r0) * K + c0;
  const unsigned short* gA1 = gA0 + (size_t)128 * K;
  const unsigned short* gB0 = Bt + (size_t)(tile_n + r0) * K + c0;
  const unsigned short* gB1 = gB0 + (size_t)128 * K;
  const int ldsA0 = (w * 64) * 8, ldsA1 = (512 + w * 64) * 8;

  auto stage = [&](unsigned short* Ab, int t) {
    unsigned short* Bb = Ab + 8192;
    const size_t ko = (size_t)t * 32;
    __builtin_amdgcn_global_load_lds((gas_ptr)(gA0 + ko), (las_ptr)&Ab[ldsA0], 16, 0, 0);
    __builtin_amdgcn_global_load_lds((gas_ptr)(gA1 + ko), (las_ptr)&Ab[ldsA1], 16, 0, 0);
    __builtin_amdgcn_global_load_lds((gas_ptr)(gB0 + ko), (las_ptr)&Bb[ldsA0], 16, 0, 0);
    __builtin_amdgcn_global_load_lds((gas_ptr)(gB1 + ko), (las_ptr)&Bb[ldsA1], 16, 0, 0);
  };

  stage(lds, 0);
  stage(lds + BUFS, 1);
  stage(lds + 2 * BUFS, 2);
  asm volatile("s_waitcnt vmcnt(8)" ::: "memory");
  __builtin_amdgcn_s_barrier();
  __builtin_amdgcn_sched_barrier(0);

  const int ca = (l4 ^ ((l15 >> 1) & 3)) * 8;

  const int nt = K >> 5;
  for (int tb = 0; tb < nt; tb += 4) {
#pragma unroll
    for (int u = 0; u < 4; u++) {
      const int t = tb + u;
      if (t + 3 < nt) stage(lds + (((u + 3) & 3) * BUFS), t + 3);

      const unsigned short* Ab = lds + u * BUFS;
      const unsigned short* Bb = Ab + 8192;
      short8 a[4], b[4], a2[4];
#pragma unroll
      for (int i = 0; i < 4; i++) {
        a[i] = *reinterpret_cast<const short8*>(&Ab[(wm * 128 + i * 16 + l15) * 32 + ca]);
        b[i] = *reinterpret_cast<const short8*>(&Bb[(wn * 64 + i * 16 + l15) * 32 + ca]);
      }
      __builtin_amdgcn_sched_barrier(0);
#pragma unroll
      for (int i = 0; i < 4; i++)
        a2[i] = *reinterpret_cast<const short8*>(&Ab[(wm * 128 + 64 + i * 16 + l15) * 32 + ca]);

      asm volatile("s_waitcnt lgkmcnt(4)" ::: "memory");
      __builtin_amdgcn_sched_barrier(0);
      __builtin_amdgcn_s_setprio(1);
#pragma unroll
      for (int mi = 0; mi < 4; mi++)
#pragma unroll
        for (int ni = 0; ni < 4; ni++)
          acc[mi][ni] = __builtin_amdgcn_mfma_f32_16x16x32_bf16(a[mi], b[ni], acc[mi][ni], 0, 0, 0);
      __builtin_amdgcn_s_setprio(0);
      __builtin_amdgcn_sched_barrier(0);

      asm volatile("s_waitcnt lgkmcnt(0)" ::: "memory");
      __builtin_amdgcn_sched_barrier(0);
      __builtin_amdgcn_s_setprio(1);
#pragma unroll
      for (int mi = 0; mi < 4; mi++)
#pragma unroll
        for (int ni = 0; ni < 4; ni++)
          acc[mi + 4][ni] = __builtin_amdgcn_mfma_f32_16x16x32_bf16(a2[mi], b[ni], acc[mi + 4][ni], 0, 0, 0);
      __builtin_amdgcn_s_setprio(0);
      __builtin_amdgcn_sched_barrier(0);

      if (t + 3 < nt) {
        asm volatile("s_waitcnt vmcnt(8)" ::: "memory");
      } else if (t + 2 < nt) {
        asm volatile("s_waitcnt vmcnt(4)" ::: "memory");
      } else if (t + 1 < nt) {
        asm volatile("s_waitcnt vmcnt(0)" ::: "memory");
      }
      __builtin_amdgcn_s_barrier();
      __builtin_amdgcn_sched_barrier(0);
    }
  }

#pragma unroll
  for (int ni = 0; ni < 4; ni++) {
    const int col = tile_n + wn * 64 + ni * 16 + l15;
    const float bv = bias[col];
#pragma unroll
    for (int mi = 0; mi < 8; mi++) {
#pragma unroll
      for (int r = 0; r < 4; r++) {
        const int row = tile_m + wm * 128 + mi * 16 + l4 * 4 + r;
        const size_t idx = (size_t)row * N + col;
        float v = acc[mi][ni][r] + bv;
        if (EP == 0) {
          ((unsigned short*)out)[idx] = f2b(v);
        } else {
          ((unsigned short*)out)[idx] = f2b(gelu_f(v));
        }
      }
    }
  }
}

// ---------------- 256x192 8-wave slim-sync GEMM (qkv) — conservative uniform waits ----------
template <int EP>
__global__ __launch_bounds__(512, 1) void gemm192_kernel(
    const unsigned short* __restrict__ A, const unsigned short* __restrict__ Bt,
    const float* __restrict__ bias, void* out, int M, int N, int K, int nx) {
  extern __shared__ unsigned short lds[];
  const int tid = threadIdx.x;
  const int lane = tid & 63, w = tid >> 6;
  const int wm = w >> 2, wn = w & 3;
  const int l15 = lane & 15, l4 = lane >> 4;

  const int nwg = gridDim.x;
  int wg = blockIdx.x;
  wg = (wg & 7) * (nwg >> 3) + (wg >> 3);
  const int tile_m = (wg / nx) * 256;
  const int tile_n = (wg % nx) * 192;

  f32x4 acc[8][3] = {};

  const bool isA = (w < 4);
  const int wl = w & 3;
  const int ch0 = wl * 64 + lane;
  const int r0 = ch0 >> 2;
  const int c0 = (((ch0 & 3) ^ ((r0 >> 1) & 3))) * 8;
  const unsigned short* G = isA ? A : Bt;
  const int tb0 = isA ? tile_m : tile_n;
  const unsigned short* g0 = G + (size_t)(tb0 + r0) * K + c0;
  const int lb = wl * 512;

  auto stage = [&](int slot, int t) {
    unsigned short* L = lds + slot * 14336 + (isA ? 0 : 8192);
    const size_t ko = (size_t)t * 32;
#pragma unroll
    for (int j = 0; j < 4; j++) {
      if (isA || j < 3)
        __builtin_amdgcn_global_load_lds((gas_ptr)(g0 + (size_t)64 * K * j + ko),
                                         (las_ptr)&L[lb + j * 2048], 16, 0, 0);
    }
  };

  stage(0, 0);
  stage(1, 1);
  stage(2, 2);
  asm volatile("s_waitcnt vmcnt(6)" ::: "memory");
  __builtin_amdgcn_s_barrier();
  __builtin_amdgcn_sched_barrier(0);

  const int ca = (l4 ^ ((l15 >> 1) & 3)) * 8;

  const int nt = K >> 5;
  for (int tb = 0; tb < nt; tb += 4) {
#pragma unroll
    for (int u = 0; u < 4; u++) {
      const int t = tb + u;
      if (t + 3 < nt) stage((u + 3) & 3, t + 3);

      const unsigned short* Ab = lds + u * 14336;
      const unsigned short* Bb = Ab + 8192;
      short8 a[4], b[3], a2[4];
#pragma unroll
      for (int i = 0; i < 4; i++)
        a[i] = *reinterpret_cast<const short8*>(&Ab[(wm * 128 + i * 16 + l15) * 32 + ca]);
#pragma unroll
      for (int i = 0; i < 3; i++)
        b[i] = *reinterpret_cast<const short8*>(&Bb[(wn * 48 + i * 16 + l15) * 32 + ca]);
      __builtin_amdgcn_sched_barrier(0);
#pragma unroll
      for (int i = 0; i < 4; i++)
        a2[i] = *reinterpret_cast<const short8*>(&Ab[(wm * 128 + 64 + i * 16 + l15) * 32 + ca]);

      asm volatile("s_waitcnt lgkmcnt(4)" ::: "memory");
      __builtin_amdgcn_sched_barrier(0);
      __builtin_amdgcn_s_setprio(1);
#pragma unroll
      for (int mi = 0; mi < 4; mi++)
#pragma unroll
        for (int ni = 0; ni < 3; ni++)
          acc[mi][ni] = __builtin_amdgcn_mfma_f32_16x16x32_bf16(a[mi], b[ni], acc[mi][ni], 0, 0, 0);
      __builtin_amdgcn_s_setprio(0);
      __builtin_amdgcn_sched_barrier(0);

      asm volatile("s_waitcnt lgkmcnt(0)" ::: "memory");
      __builtin_amdgcn_sched_barrier(0);
      __builtin_amdgcn_s_setprio(1);
#pragma unroll
      for (int mi = 0; mi < 4; mi++)
#pragma unroll
        for (int ni = 0; ni < 3; ni++)
          acc[mi + 4][ni] = __builtin_amdgcn_mfma_f32_16x16x32_bf16(a2[mi], b[ni], acc[mi + 4][ni], 0, 0, 0);
      __builtin_amdgcn_s_setprio(0);
      __builtin_amdgcn_sched_barrier(0);

      if (t + 3 < nt) {
        asm volatile("s_waitcnt vmcnt(6)" ::: "memory");
      } else if (t + 2 < nt) {
        asm volatile("s_waitcnt vmcnt(3)" ::: "memory");
      } else if (t + 1 < nt) {
        asm volatile("s_waitcnt vmcnt(0)" ::: "memory");
      }
      __builtin_amdgcn_s_barrier();
      __builtin_amdgcn_sched_barrier(0);
    }
  }

#pragma unroll
  for (int ni = 0; ni < 3; ni++) {
    const int col = tile_n + wn * 48 + ni * 16 + l15;
    const float bv = bias[col];
#pragma unroll
    for (int mi = 0; mi < 8; mi++) {
#pragma unroll
      for (int r = 0; r < 4; r++) {
        const int row = tile_m + wm * 128 + mi * 16 + l4 * 4 + r;
        const size_t idx = (size_t)row * N + col;
        float v = acc[mi][ni][r] + bv;
        if (EP == 0) {
          ((unsigned short*)out)[idx] = f2b(v);
        } else {
          ((unsigned short*)out)[idx] = f2b(gelu_f(v));
        }
      }
    }
  }
}

// ---------------- 128^2 GEMM — R13 pair-processing (projections) ----------------
__global__ __launch_bounds__(512, 1) void gemm128_kernel(
    const unsigned short* __restrict__ A, const unsigned short* __restrict__ Bt,
    const float* __restrict__ bias, const float* __restrict__ res, float* __restrict__ out,
    int M, int N, int K, int nx) {
  extern __shared__ unsigned short lds[];
  const int tid = threadIdx.x;
  const int lane = tid & 63, w = tid >> 6;
  const int wm = w >> 2, wn = w & 3;
  const int l15 = lane & 15, l4 = lane >> 4;

  const int nwg = gridDim.x;
  int wg = blockIdx.x;
  wg = (wg & 7) * (nwg >> 3) + (wg >> 3);
  const int tile_m = (wg / nx) * 128;
  const int tile_n = (wg % nx) * 128;

  f32x4 acc[4][2] = {};

  const unsigned short* Gs = (w < 4) ? A : Bt;
  const int tb0 = (w < 4) ? tile_m : tile_n;
  const int ch0 = (w & 3) * 128 + lane;
  const int r0c = ch0 >> 2;
  const int c0s = (((ch0 & 3) ^ ((r0c >> 1) & 3))) * 8;
  const unsigned short* g0 = Gs + (size_t)(tb0 + r0c) * K + c0s;
  const unsigned short* g1 = g0 + (size_t)16 * K;
  const int lds0 = ((w & 3) * 128) * 8, lds1 = ((w & 3) * 128 + 64) * 8;
  const int half = (w < 4) ? 0 : 4096;

  auto stage = [&](int slot, int t) {
    unsigned short* Lb = lds + slot * 8192 + half;
    const size_t ko = (size_t)t * 32;
    __builtin_amdgcn_global_load_lds((gas_ptr)(g0 + ko), (las_ptr)&Lb[lds0], 16, 0, 0);
    __builtin_amdgcn_global_load_lds((gas_ptr)(g1 + ko), (las_ptr)&Lb[lds1], 16, 0, 0);
  };

  stage(0, 0);
  stage(1, 1);
  stage(2, 2);
  stage(3, 3);
  asm volatile("s_waitcnt vmcnt(4)" ::: "memory");
  __builtin_amdgcn_s_barrier();
  __builtin_amdgcn_sched_barrier(0);

  const int ca = (l4 ^ ((l15 >> 1) & 3)) * 8;

  const int nt = K >> 5;
  const int np = nt >> 1;
  for (int p = 0; p < np; ++p) {
    const int t0 = 2 * p;
    if (t0 + 4 < nt) stage((t0 + 4) % 6, t0 + 4);
    if (t0 + 5 < nt) stage((t0 + 5) % 6, t0 + 5);

    const unsigned short* A0 = lds + (t0 % 6) * 8192;
    const unsigned short* B0 = A0 + 4096;
    const unsigned short* A1 = lds + ((t0 + 1) % 6) * 8192;
    const unsigned short* B1 = A1 + 4096;
    short8 a[2], b[2], a2[2], c[2], d[2], c2[2];
#pragma unroll
    for (int i = 0; i < 2; i++) {
      a[i] = *reinterpret_cast<const short8*>(&A0[(wm * 64 + i * 16 + l15) * 32 + ca]);
      b[i] = *reinterpret_cast<const short8*>(&B0[(wn * 32 + i * 16 + l15) * 32 + ca]);
    }
    __builtin_amdgcn_sched_barrier(0);
#pragma unroll
    for (int i = 0; i < 2; i++)
      a2[i] = *reinterpret_cast<const short8*>(&A0[(wm * 64 + 32 + i * 16 + l15) * 32 + ca]);
    __builtin_amdgcn_sched_barrier(0);
#pragma unroll
    for (int i = 0; i < 2; i++) {
      c[i] = *reinterpret_cast<const short8*>(&A1[(wm * 64 + i * 16 + l15) * 32 + ca]);
      d[i] = *reinterpret_cast<const short8*>(&B1[(wn * 32 + i * 16 + l15) * 32 + ca]);
    }
    __builtin_amdgcn_sched_barrier(0);
#pragma unroll
    for (int i = 0; i < 2; i++)
      c2[i] = *reinterpret_cast<const short8*>(&A1[(wm * 64 + 32 + i * 16 + l15) * 32 + ca]);

    asm volatile("s_waitcnt lgkmcnt(8)" ::: "memory");
    __builtin_amdgcn_sched_barrier(0);
    __builtin_amdgcn_s_setprio(1);
#pragma unroll
    for (int mi = 0; mi < 2; mi++)
#pragma unroll
      for (int ni = 0; ni < 2; ni++)
        acc[mi][ni] = __builtin_amdgcn_mfma_f32_16x16x32_bf16(a[mi], b[ni], acc[mi][ni], 0, 0, 0);
    __builtin_amdgcn_s_setprio(0);
    __builtin_amdgcn_sched_barrier(0);

    asm volatile("s_waitcnt lgkmcnt(6)" ::: "memory");
    __builtin_amdgcn_sched_barrier(0);
    __builtin_amdgcn_s_setprio(1);
#pragma unroll
    for (int mi = 0; mi < 2; mi++)
#pragma unroll
      for (int ni = 0; ni < 2; ni++)
        acc[mi + 2][ni] = __builtin_amdgcn_mfma_f32_16x16x32_bf16(a2[mi], b[ni], acc[mi + 2][ni], 0, 0, 0);
    __builtin_amdgcn_s_setprio(0);
    __builtin_amdgcn_sched_barrier(0);

    asm volatile("s_waitcnt lgkmcnt(2)" ::: "memory");
    __builtin_amdgcn_sched_barrier(0);
    __builtin_amdgcn_s_setprio(1);
#pragma unroll
    for (int mi = 0; mi < 2; mi++)
#pragma unroll
      for (int ni = 0; ni < 2; ni++)
        acc[mi][ni] = __builtin_amdgcn_mfma_f32_16x16x32_bf16(c[mi], d[ni], acc[mi][ni], 0, 0, 0);
    __builtin_amdgcn_s_setprio(0);
    __builtin_amdgcn_sched_barrier(0);

    asm volatile("s_waitcnt lgkmcnt(0)" ::: "memory");
    __builtin_amdgcn_sched_barrier(0);
    __builtin_amdgcn_s_setprio(1);
#pragma unroll
    for (int mi = 0; mi < 2; mi++)
#pragma unroll
      for (int ni = 0; ni < 2; ni++)
        acc[mi + 2][ni] = __builtin_amdgcn_mfma_f32_16x16x32_bf16(c2[mi], d[ni], acc[mi + 2][ni], 0, 0, 0);
    __builtin_amdgcn_s_setprio(0);
    __builtin_amdgcn_sched_barrier(0);

    if (t0 + 4 < nt) {
      asm volatile("s_waitcnt vmcnt(4)" ::: "memory");
    } else if (t0 + 2 < nt) {
      asm volatile("s_waitcnt vmcnt(0)" ::: "memory");
    }
    __builtin_amdgcn_s_barrier();
    __builtin_amdgcn_sched_barrier(0);
  }

#pragma unroll
  for (int ni = 0; ni < 2; ni++) {
    const int col = tile_n + wn * 32 + ni * 16 + l15;
    const float bv = bias[col];
#pragma unroll
    for (int mi = 0; mi < 4; mi++) {
#pragma unroll
      for (int r = 0; r < 4; r++) {
        const int row = tile_m + wm * 64 + mi * 16 + l4 * 4 + r;
        const size_t idx = (size_t)row * N + col;
        out[idx] = acc[mi][ni][r] + bv + res[idx];
      }
    }
  }
}

// ---------------- Strided-sparse flash attention v3 + T13 (R13/R16 proven) ----------------
__global__ __launch_bounds__(256, 4) void attn_kernel(const unsigned short* __restrict__ qkv,
                                                      unsigned short* __restrict__ y) {
  __shared__ unsigned short SH[17408];
  const int tid = threadIdx.x;
  const int lane = tid & 63, w = tid >> 6;
  const int l15 = lane & 15, l4 = lane >> 4;

  const int bi = blockIdx.x;
  const int quarter = bi >> 8, rest = bi & 255;
  const int bh = rest >> 3, sub = rest & 7;
  int qt;
  if (quarter == 0) qt = sub;
  else if (quarter == 1) qt = 15 - sub;
  else if (quarter == 2) qt = 16 + sub;
  else qt = 31 - sub;
  const int bb = bh >> 4, hh = bh & 15;
  const int q0 = qt * 64;
  const size_t base = (size_t)bb * Tn * (3 * Cn) + hh * 64;

  const int nfar = qt >> 1;
  const int ntiles = nfar + (q0 ? 2 : 1);

  unsigned short* Vt = SH + 8192;
  unsigned short* Ps = SH + 12800 + w * 1152;

  auto keyof = [&](int t, int row) -> int {
    if (t < nfar) return t * 128 + 2 * row;
    return q0 - 64 * (ntiles - 1 - t) + row;
  };
  auto stageK = [&](int t) {
    unsigned short* kb = SH + ((t & 1) << 12);
#pragma unroll
    for (int u = 0; u < 2; u++) {
      const int chunk = u * 256 + tid;
      const int row = chunk >> 3, cc = chunk & 7;
      const int csrc = cc ^ (row & 7);
      const int key = keyof(t, row);
      __builtin_amdgcn_global_load_lds(
          (gas_ptr)&qkv[base + Cn + (size_t)key * (3 * Cn) + csrc * 8],
          (las_ptr)&kb[(u * 256 + (w << 6)) * 8], 16, 0, 0);
    }
  };
  uint4 vr[2];
  auto fetchV = [&](int t) {
#pragma unroll
    for (int u = 0; u < 2; u++) {
      const int chunk = u * 256 + tid;
      const int row = chunk >> 3, cc = chunk & 7;
      const int key = keyof(t, row);
      vr[u] = *reinterpret_cast<const uint4*>(&qkv[base + 2 * Cn + (size_t)key * (3 * Cn) + cc * 8]);
    }
  };

#pragma unroll
  for (int u = 0; u < 2; u++) {
    const int chunk = u * 256 + tid;
    const int row = chunk >> 3, cc = chunk & 7;
    const int csrc = cc ^ (row & 7);
    __builtin_amdgcn_global_load_lds(
        (gas_ptr)&qkv[base + (size_t)(q0 + row) * (3 * Cn) + csrc * 8],
        (las_ptr)&SH[(u * 256 + (w << 6)) * 8], 16, 0, 0);
  }
  __syncthreads();
  short8 qf[2];
#pragma unroll
  for (int ks = 0; ks < 2; ks++) {
    const int r = (w << 4) + l15;
    qf[ks] = *reinterpret_cast<const short8*>(&SH[r * 64 + (((ks * 4 + l4) ^ (l15 & 7)) * 8)]);
  }
  asm volatile("s_waitcnt lgkmcnt(0)" ::: "memory");
  __builtin_amdgcn_s_barrier();
  __builtin_amdgcn_sched_barrier(0);
  stageK(0);
  fetchV(0);
  __syncthreads();

  f32x4 acc_o[4] = {};
  float mrow[4], lrow[4];
#pragma unroll
  for (int r = 0; r < 4; r++) { mrow[r] = -1e30f; lrow[r] = 0.0f; }

  for (int t = 0; t < ntiles; ++t) {
#pragma unroll
    for (int u = 0; u < 2; u++) {
      const int chunk = u * 256 + tid;
      const int row = chunk >> 3, cc = chunk & 7;
      unsigned short tmp[8];
      *reinterpret_cast<uint4*>(tmp) = vr[u];
      const int xr = row ^ (cc << 3);
#pragma unroll
      for (int j = 0; j < 8; j++) Vt[(cc * 8 + j) * 72 + xr] = tmp[j];
    }
    if (t + 1 < ntiles) { stageK(t + 1); fetchV(t + 1); }
    asm volatile("s_waitcnt lgkmcnt(0)" ::: "memory");
    __builtin_amdgcn_s_barrier();
    __builtin_amdgcn_sched_barrier(0);

    const unsigned short* Kb = SH + ((t & 1) << 12);
    f32x4 s[4] = {};
#pragma unroll
    for (int ni = 0; ni < 4; ni++) {
#pragma unroll
      for (int ks = 0; ks < 2; ks++) {
        const int r = ni * 16 + l15;
        short8 kf = *reinterpret_cast<const short8*>(&Kb[r * 64 + (((ks * 4 + l4) ^ (l15 & 7)) * 8)]);
        s[ni] = __builtin_amdgcn_mfma_f32_16x16x32_bf16(qf[ks], kf, s[ni], 0, 0, 0);
      }
    }

    const bool far = (t < nfar);
    const int kb0 = far ? t * 128 : q0 - 64 * (ntiles - 1 - t);
#pragma unroll
    for (int ni = 0; ni < 4; ni++) {
      const int pos = ni * 16 + l15;
      const int j = far ? kb0 + 2 * pos : kb0 + pos;
#pragma unroll
      for (int r = 0; r < 4; r++) {
        float v = s[ni][r] * 0.125f;
        if (far) {
          v = (j < q0 - 64) ? v : -1e30f;
        } else {
          const int iq = q0 + (w << 4) + l4 * 4 + r;
          const bool ok = (j <= iq) && ((j >= iq - 4) || ((j & 1) == 0));
          v = ok ? v : -1e30f;
        }
        s[ni][r] = v;
      }
    }

    float tmx[4];
    bool need = false;
#pragma unroll
    for (int r = 0; r < 4; r++) {
      float tm = fmaxf(fmaxf(s[0][r], s[1][r]), fmaxf(s[2][r], s[3][r]));
      tm = fmaxf(tm, __shfl_xor(tm, 1));
      tm = fmaxf(tm, __shfl_xor(tm, 2));
      tm = fmaxf(tm, __shfl_xor(tm, 4));
      tm = fmaxf(tm, __shfl_xor(tm, 8));
      tmx[r] = tm;
      need = need || (tm > mrow[r] + 8.0f);
    }
    if (__any(need)) {
#pragma unroll
      for (int r = 0; r < 4; r++) {
        const float mnew = fmaxf(mrow[r], tmx[r]);
        const float alpha = __expf(mrow[r] - mnew);
        mrow[r] = mnew;
        lrow[r] *= alpha;
#pragma unroll
        for (int nd = 0; nd < 4; nd++) acc_o[nd][r] *= alpha;
      }
    }
#pragma unroll
    for (int r = 0; r < 4; r++) {
      float rs = 0.0f;
#pragma unroll
      for (int ni = 0; ni < 4; ni++) {
        const float pv = __expf(s[ni][r] - mrow[r]);
        s[ni][r] = pv;
        rs += pv;
      }
      rs += __shfl_xor(rs, 1); rs += __shfl_xor(rs, 2);
      rs += __shfl_xor(rs, 4); rs += __shfl_xor(rs, 8);
      lrow[r] += rs;
    }

#pragma unroll
    for (int ni = 0; ni < 4; ni++)
#pragma unroll
      for (int r = 0; r < 4; r++)
        Ps[(l4 * 4 + r) * 72 + ni * 16 + l15] = f2b(s[ni][r]);

#pragma unroll
    for (int kss = 0; kss < 2; kss++) {
      short8 pf = *reinterpret_cast<const short8*>(&Ps[l15 * 72 + kss * 32 + l4 * 8]);
#pragma unroll
      for (int nd = 0; nd < 4; nd++) {
        const int d = nd * 16 + l15;
        const int kcol = (kss * 32 + l4 * 8) ^ ((d >> 3) << 3);
        short8 vf = *reinterpret_cast<const short8*>(&Vt[d * 72 + kcol]);
        acc_o[nd] = __builtin_amdgcn_mfma_f32_16x16x32_bf16(pf, vf, acc_o[nd], 0, 0, 0);
      }
    }

    __syncthreads();
  }

#pragma unroll
  for (int r = 0; r < 4; r++) {
    const float inv = 1.0f / lrow[r];
    const int row = q0 + (w << 4) + l4 * 4 + r;
#pragma unroll
    for (int nd = 0; nd < 4; nd++) {
      const int col = nd * 16 + l15;
      y[((size_t)bb * Tn + row) * Cn + hh * 64 + col] = f2b(acc_o[nd][r] * inv);
    }
  }
}

// ---------------- launch ----------------
extern "C" void kernel_launch(void* const* d_in, const int* in_sizes, int n_in,
                              void* d_out, int out_size, void* d_ws, size_t ws_size,
                              hipStream_t stream) {
  const float* x           = (const float*)d_in[0];
  const float* ln1_w       = (const float*)d_in[1];
  const float* ln1_b       = (const float*)d_in[2];
  const float* c_attn_w    = (const float*)d_in[3];
  const float* c_attn_b    = (const float*)d_in[4];
  const float* attn_proj_w = (const float*)d_in[5];
  const float* attn_proj_b = (const float*)d_in[6];
  const float* ln2_w       = (const float*)d_in[7];
  const float* ln2_b       = (const float*)d_in[8];
  const float* fc_w        = (const float*)d_in[9];
  const float* fc_b        = (const float*)d_in[10];
  const float* mlp_proj_w  = (const float*)d_in[11];
  const float* mlp_proj_b  = (const float*)d_in[12];
  float* out = (float*)d_out;

  char* ws = (char*)d_ws;
  unsigned short* wT1 = (unsigned short*)(ws);                     // [3072][1024]
  unsigned short* wT2 = (unsigned short*)(ws + 6291456);           // [1024][1024]
  unsigned short* wT3 = (unsigned short*)(ws + 8388608);           // [4096][1024]
  unsigned short* wT4 = (unsigned short*)(ws + 16777216);          // [1024][4096]
  unsigned short* h   = (unsigned short*)(ws + 25165824);          // [4096][1024]
  unsigned short* qkv = (unsigned short*)(ws + 33554432);          // [4096][3072] / [4096][4096]
  unsigned short* yb  = (unsigned short*)(ws + 67108864);          // [4096][1024]

  hipFuncSetAttribute((const void*)gemm192_kernel<0>, hipFuncAttributeMaxDynamicSharedMemorySize, 114688);
  hipFuncSetAttribute((const void*)gemm256_kernel<2>, hipFuncAttributeMaxDynamicSharedMemorySize, 131072);
  hipFuncSetAttribute((const void*)gemm128_kernel, hipFuncAttributeMaxDynamicSharedMemorySize, 98304);

  prep_kernel<<<16384, 256, 0, stream>>>(c_attn_w, wT1, attn_proj_w, wT2,
                                         fc_w, wT3, mlp_proj_w, wT4,
                                         x, ln1_w, ln1_b, h);
  // qkv = h @ c_attn_w + b   (256x192 tile, grid 256)
  gemm192_kernel<0><<<(Mrows / 256) * (3072 / 192), 512, 114688, stream>>>(
      h, wT1, c_attn_b, qkv, Mrows, 3072, 1024, 3072 / 192);
  attn_kernel<<<1024, 256, 0, stream>>>(qkv, yb);
  gemm128_kernel<<<(Mrows / 128) * (1024 / 128), 512, 98304, stream>>>(
      yb, wT2, attn_proj_b, x, out, Mrows, 1024, 1024, 1024 / 128);
  ln_kernel<<<Mrows, 256, 0, stream>>>(out, ln2_w, ln2_b, h);
  gemm256_kernel<2><<<(Mrows / 256) * (4096 / 256), 512, 131072, stream>>>(
      h, wT3, fc_b, qkv, Mrows, 4096, 1024, 4096 / 256);
  gemm128_kernel<<<(Mrows / 128) * (1024 / 128), 512, 98304, stream>>>(
      qkv, wT4, mlp_proj_b, out, out, Mrows, 1024, 4096, 1024 / 128);
}